// Round 1
// baseline (227.281 us; speedup 1.0000x reference)
//
#include <hip/hip_runtime.h>

// RoPE: out[..., 2k]   = cos*x[...,2k] - sin*x[...,2k+1]
//       out[..., 2k+1] = sin*x[...,2k] + cos*x[...,2k+1]
// x: (4,16,4096,128) fp32, tables: (8192,64) fp32, token_positions: (4096,) i32.
// Memory-bound: 128 MiB in + 128 MiB out; tables ~1 MiB live set (L2-resident).

constexpr int SEQ      = 4096;
constexpr int D_K      = 128;
constexpr int F4_PER_ROW = D_K / 4;   // 32 float4 per row

__global__ __launch_bounds__(256) void rope_kernel(
    const float4* __restrict__ x,
    const int*    __restrict__ tok_pos,
    const float2* __restrict__ cos_t,   // (8192, 32) as float2
    const float2* __restrict__ sin_t,
    float4*       __restrict__ out)
{
    const int i = blockIdx.x * blockDim.x + threadIdx.x;  // float4 index

    const int within = i & (F4_PER_ROW - 1);   // which float4 in the 128-float row
    const int row    = i >> 5;                 // (b*H + h)*SEQ + s
    const int s      = row & (SEQ - 1);        // SEQ = 4096 (pow2)
    const int p      = tok_pos[s];             // honor the gather

    // Each float4 covers pairs k = 2*within and 2*within+1 -> float2 of tables.
    const float2 c  = cos_t[p * (D_K / 4) + within];
    const float2 sn = sin_t[p * (D_K / 4) + within];

    const float4 v = x[i];
    float4 o;
    o.x = c.x * v.x - sn.x * v.y;
    o.y = sn.x * v.x + c.x * v.y;
    o.z = c.y * v.z - sn.y * v.w;
    o.w = sn.y * v.z + c.y * v.w;
    out[i] = o;
}

extern "C" void kernel_launch(void* const* d_in, const int* in_sizes, int n_in,
                              void* d_out, int out_size, void* d_ws, size_t ws_size,
                              hipStream_t stream) {
    const float4* x       = (const float4*)d_in[0];
    const int*    tok_pos = (const int*)d_in[1];
    const float2* cos_t   = (const float2*)d_in[2];
    const float2* sin_t   = (const float2*)d_in[3];
    float4*       out     = (float4*)d_out;

    const int n4 = out_size / 4;              // 8,388,608 float4s
    const int block = 256;
    const int grid  = n4 / block;             // exact: n4 % 256 == 0

    rope_kernel<<<grid, block, 0, stream>>>(x, tok_pos, cos_t, sin_t, out);
}